// Round 4
// baseline (2566.552 us; speedup 1.0000x reference)
//
#include <hip/hip_runtime.h>

typedef __attribute__((ext_vector_type(8))) short short8;
typedef __attribute__((ext_vector_type(4))) float f32x4;
typedef __attribute__((ext_vector_type(2))) unsigned long long u64x2;
typedef unsigned short u16;
typedef unsigned int u32;
typedef unsigned long long u64;

#define T_LEN 256
#define STEP_U16 32768          // one step's fragment set: 16kt*4nt*512 u16 = 64KB
#define CHUNK_U16 512

// workspace layout (bytes)
#define OFF_X0 0u
#define SZ_X0 (256u * 65536u)   // x0 fragments [t][kt][nt][lane][8] bf16, 16MB
#define OFF_Y0 (OFF_X0 + SZ_X0)
#define SZ_Y0 SZ_X0             // y (o-gate) fragments, 16MB
#define OFF_HD (OFF_Y0 + SZ_Y0)
#define SZ_HD (4u * 65536u)     // h ring: [layer][slot] 64KB each = 256KB
#define OFF_POOL (OFF_HD + SZ_HD)
#define SZ_POOL (512u * 64u * 4u)
#define OFF_FLG (OFF_POOL + SZ_POOL)
#define SZ_FLG (4u * 128u * 4u) // [layer*2+sb][128 producer waves] u32

__device__ __forceinline__ u16 f2bf(float x) {
  unsigned u = __builtin_bit_cast(unsigned, x);
  return (u16)((u + 0x7fffu + ((u >> 16) & 1u)) >> 16);
}
__device__ __forceinline__ float sigf(float x) { return 1.f / (1.f + __expf(-x)); }
__device__ __forceinline__ float tanhfast(float x) {
  float e = __expf(2.f * x);
  return 1.f - 2.f / (e + 1.f);
}

// LLC-coherent 16B load as 2x relaxed agent-scope 64-bit atomic loads (sc1).
__device__ __forceinline__ short8 ld16_llc(const u16* p) {
  const u64* q = (const u64*)p;
  u64x2 u;
  u[0] = __hip_atomic_load(q + 0, __ATOMIC_RELAXED, __HIP_MEMORY_SCOPE_AGENT);
  u[1] = __hip_atomic_load(q + 1, __ATOMIC_RELAXED, __HIP_MEMORY_SCOPE_AGENT);
  return __builtin_bit_cast(short8, u);
}
__device__ __forceinline__ void st2_llc(u16* p, u16 v) {
  __hip_atomic_store(p, v, __ATOMIC_RELAXED, __HIP_MEMORY_SCOPE_AGENT);
}

__device__ __forceinline__ short8 cvt8(const float* src) {
  float4 lo = *(const float4*)src;
  float4 hi = *(const float4*)(src + 4);
  short8 fr;
  fr[0] = (short)f2bf(lo.x); fr[1] = (short)f2bf(lo.y);
  fr[2] = (short)f2bf(lo.z); fr[3] = (short)f2bf(lo.w);
  fr[4] = (short)f2bf(hi.x); fr[5] = (short)f2bf(hi.y);
  fr[6] = (short)f2bf(hi.z); fr[7] = (short)f2bf(hi.w);
  return fr;
}

// ---- embedding gather into MFMA-B fragment layout (bf16) ----
__global__ void gather_x0(const int* __restrict__ in_t, const float* __restrict__ emb,
                          u16* __restrict__ x0) {
  int gid = blockIdx.x * 256 + threadIdx.x;
  int c = gid >> 6, lane = gid & 63;
  int t = c >> 6, rem = c & 63;
  int kt = rem >> 2, nt = rem & 3;
  int b = nt * 16 + (lane & 15);
  int k0 = kt * 32 + ((lane >> 4) * 8);
  int row = in_t[b * T_LEN + t];
  *(short8*)(x0 + (size_t)c * CHUNK_U16 + lane * 8) =
      cvt8(emb + (size_t)row * 512 + k0);
}

// ---- persistent recurrent kernel ----
// 128 blocks x 512 threads. bid: layer=(bid&3)>>1, sb=bid&1, rb=bid>>2 (0..31).
// Block: h-indices [16rb,16rb+16) x samples [32sb,32sb+32).
// Rows gate-interleaved: row = 4*h_local + gate.
// Waves 0-3: x-side (K 0..511, Wx), m-tile = w&3, compute step t+1 -> LDS part.
// Waves 4-7: h-side (K 512..1023, Wh), m-tile = w&3, critical path.
__global__ __launch_bounds__(512, 1) void lstm_persist(
    const float* __restrict__ wx, const float* __restrict__ bx,
    const float* __restrict__ wh, const float* __restrict__ bh,
    const u16* __restrict__ x0, u16* __restrict__ y0,
    u16* __restrict__ hd, float* __restrict__ pool, u32* __restrict__ flg) {
  __shared__ float part[2][64][32];   // [parity][row][sample]

  const int tid = threadIdx.x;
  const int w = tid >> 6, lane = tid & 63;
  const int side = w >> 2, mt = w & 3;
  const int bid = blockIdx.x;
  const int layer = (bid & 3) >> 1;
  const int sb = bid & 1;
  const int rb = bid >> 2;
  const int q = lane >> 4, col = lane & 15;

  // ---- weight fragments: m-tile mt, this side's K-half ----
  short8 afrag[16];
  {
    const int m = lane & 15;
    const int h_l = rb * 16 + mt * 4 + (m >> 2);
    const int g_l = m & 3;
    const float* wrow = (side == 0 ? wx : wh) +
                        ((size_t)(layer * 4 + g_l) * 512 + h_l) * 512;
#pragma unroll
    for (int kt = 0; kt < 16; ++kt)
      afrag[kt] = cvt8(wrow + kt * 32 + q * 8);
  }
  const int h_own = rb * 16 + mt * 4 + q;
  float bias_r[4];
#pragma unroll
  for (int r = 0; r < 4; ++r)
    bias_r[r] = bx[(layer * 4 + r) * 512 + h_own] + bh[(layer * 4 + r) * 512 + h_own];

  const u16* xl = (layer == 0) ? x0 : y0;
  u16* hdl = hd + (size_t)layer * 2 * STEP_U16;
  u32* fl_own = flg + (layer * 2 + sb) * 128 + rb * 4 + mt;
  const u64* fl_grp = (const u64*)(flg + (layer * 2 + sb) * 128);
  const u64* fl_y = (const u64*)(flg + (0 * 2 + sb) * 128);

  float2 cst = {0.f, 0.f};
  float2 opool = {0.f, 0.f};

  // ---- x-side body: compute x-partials for step tf into part[tf&1] ----
  auto x_phase = [&](int tf) {
    if (layer == 1) {
      const u32 tgt = (u32)(tf + 1);
      for (;;) {
        u64 v = __hip_atomic_load(fl_y + lane, __ATOMIC_RELAXED,
                                  __HIP_MEMORY_SCOPE_AGENT);
        if (__all((int)(((u32)v >= tgt) & ((u32)(v >> 32) >= tgt)))) break;
        __builtin_amdgcn_s_sleep(1);
      }
      asm volatile("" ::: "memory");
    }
    const u16* xs = xl + (size_t)tf * STEP_U16;
    f32x4 acc[2] = {};
#pragma unroll
    for (int kt = 0; kt < 16; ++kt) {
#pragma unroll
      for (int ntl = 0; ntl < 2; ++ntl) {
        const u16* p = xs + ((size_t)(kt * 4 + 2 * sb + ntl) * 64 + lane) * 8;
        short8 bf = (layer == 0) ? *(const short8*)p : ld16_llc(p);
        acc[ntl] = __builtin_amdgcn_mfma_f32_16x16x32_bf16(afrag[kt], bf,
                                                           acc[ntl], 0, 0, 0);
      }
    }
    const int par = tf & 1;
#pragma unroll
    for (int ntl = 0; ntl < 2; ++ntl)
#pragma unroll
      for (int r = 0; r < 4; ++r)
        part[par][mt * 16 + q * 4 + r][ntl * 16 + col] = acc[ntl][r];
  };

  if (side == 0) x_phase(0);   // prologue: x-partials for t=0
  __syncthreads();

  for (int t = 0; t < T_LEN; ++t) {
    if (side == 0) {
      if (t < T_LEN - 1) x_phase(t + 1);
    } else {
      // ---- h-side critical path ----
      {
        const u32 tgt = (u32)t;
        for (;;) {
          u64 v = __hip_atomic_load(fl_grp + lane, __ATOMIC_RELAXED,
                                    __HIP_MEMORY_SCOPE_AGENT);
          if (__all((int)(((u32)v >= tgt) & ((u32)(v >> 32) >= tgt)))) break;
          __builtin_amdgcn_s_sleep(1);
        }
        asm volatile("" ::: "memory");
      }
      const u16* hs = hdl + (size_t)(t & 1) * STEP_U16;
      f32x4 acc[2] = {};
#pragma unroll
      for (int kt = 0; kt < 16; ++kt) {
#pragma unroll
        for (int ntl = 0; ntl < 2; ++ntl) {
          short8 bf = ld16_llc(hs + ((size_t)(kt * 4 + 2 * sb + ntl) * 64 + lane) * 8);
          acc[ntl] = __builtin_amdgcn_mfma_f32_16x16x32_bf16(afrag[kt], bf,
                                                             acc[ntl], 0, 0, 0);
        }
      }
      const int par = t & 1;
      u16* hdst = hdl + (size_t)((t + 1) & 1) * STEP_U16;
      const int kt2 = h_own >> 5, j = h_own & 7;
      const int lp = col + 16 * ((h_own >> 3) & 3);
#pragma unroll
      for (int ntl = 0; ntl < 2; ++ntl) {
        const int nt = 2 * sb + ntl;
        float v[4];
#pragma unroll
        for (int r = 0; r < 4; ++r)
          v[r] = acc[ntl][r] + part[par][mt * 16 + q * 4 + r][ntl * 16 + col] +
                 bias_r[r];
        const float ig = sigf(v[0]);
        const float fg = sigf(v[1]);
        const float gg = tanhfast(v[2]);
        const float og = sigf(v[3]);
        const float cp = ntl ? cst.y : cst.x;
        const float cn = fg * cp + ig * gg;   // c input = prev h_new (unpack bug)
        const float hn = og * tanhfast(cn);
        if (ntl) cst.y = hn; else cst.x = hn;
        const size_t off = ((size_t)(kt2 * 4 + nt) * 64 + lp) * 8 + j;
        st2_llc(hdst + off, f2bf(cn));        // c_new -> next h-input (bug)
        if (layer == 0) {
          st2_llc(y0 + (size_t)t * STEP_U16 + off, f2bf(og));  // o -> L1 input
        } else {
          if (ntl) opool.y += og; else opool.x += og;
        }
      }
      asm volatile("s_waitcnt vmcnt(0)" ::: "memory");
      if (lane == 0)
        __hip_atomic_store(fl_own, (u32)(t + 1), __ATOMIC_RELAXED,
                           __HIP_MEMORY_SCOPE_AGENT);
    }
    __syncthreads();
  }

  if (layer == 1 && side == 1) {
#pragma unroll
    for (int ntl = 0; ntl < 2; ++ntl)
      pool[(size_t)h_own * 64 + sb * 32 + ntl * 16 + col] =
          (ntl ? opool.y : opool.x);
  }
}

// ---- final pooled @ wo.T + bo -> sigmoid ----
__global__ void finalize_k(const float* __restrict__ pool, const float* __restrict__ wo,
                           const float* __restrict__ bo, float* __restrict__ out) {
  const int b = threadIdx.x;
  float s = 0.f;
  for (int h = 0; h < 512; ++h) s += pool[h * 64 + b] * wo[h];
  out[b] = sigf(s * (1.f / 256.f) + bo[0]);
}

extern "C" void kernel_launch(void* const* d_in, const int* in_sizes, int n_in,
                              void* d_out, int out_size, void* d_ws, size_t ws_size,
                              hipStream_t stream) {
  const int* in_t = (const int*)d_in[0];
  const float* emb = (const float*)d_in[1];
  const float* wx = (const float*)d_in[2];
  const float* bx = (const float*)d_in[3];
  const float* wh = (const float*)d_in[4];
  const float* bh = (const float*)d_in[5];
  const float* wo = (const float*)d_in[6];
  const float* bo = (const float*)d_in[7];
  float* out = (float*)d_out;
  char* ws = (char*)d_ws;
  u16* x0 = (u16*)(ws + OFF_X0);
  u16* y0 = (u16*)(ws + OFF_Y0);
  u16* hd = (u16*)(ws + OFF_HD);
  float* pool = (float*)(ws + OFF_POOL);
  u32* flg = (u32*)(ws + OFF_FLG);

  hipMemsetAsync(ws + OFF_HD, 0, SZ_HD, stream);    // h(0) = 0
  hipMemsetAsync(ws + OFF_FLG, 0, SZ_FLG, stream);  // step flags
  gather_x0<<<4096, 256, 0, stream>>>(in_t, emb, x0);
  lstm_persist<<<128, 512, 0, stream>>>(wx, bx, wh, bh, x0, y0, hd, pool, flg);
  finalize_k<<<1, 64, 0, stream>>>(pool, wo, bo, out);
}